// Round 3
// baseline (101.837 us; speedup 1.0000x reference)
//
#include <hip/hip_runtime.h>
#include <hip/hip_bf16.h>
#include <math.h>

typedef __bf16 bf16_t;
typedef __bf16 bf16x8 __attribute__((ext_vector_type(8)));
typedef float floatx4 __attribute__((ext_vector_type(4)));
typedef unsigned int u32;

#define NHEAD 16

// async global->LDS, 16B per lane. Dest must be wave-uniform base + lane*16.
__device__ __forceinline__ void gload_lds16(const void* g, void* l) {
    __builtin_amdgcn_global_load_lds((const __attribute__((address_space(1))) u32*)g,
                                     (__attribute__((address_space(3))) u32*)l, 16, 0, 0);
}

// raw barrier with compiler + scheduler fences (no vmcnt drain — loads stay in flight)
__device__ __forceinline__ void bar() {
    __builtin_amdgcn_sched_barrier(0);
    asm volatile("" ::: "memory");
    __builtin_amdgcn_s_barrier();
    asm volatile("" ::: "memory");
    __builtin_amdgcn_sched_barrier(0);
}

// ---------------- fused prep: fp32->bf16 converts (7 tensors) + RoPE table ----------------
__global__ __launch_bounds__(256) void k_prep(
    const float* __restrict__ q, const float* __restrict__ k, const float* __restrict__ v,
    const float* __restrict__ wq, const float* __restrict__ wk,
    const float* __restrict__ wv, const float* __restrict__ wo,
    bf16_t* __restrict__ Xq, bf16_t* __restrict__ Xk, bf16_t* __restrict__ Xv,
    bf16_t* __restrict__ Wqb, bf16_t* __restrict__ Wkb, bf16_t* __restrict__ Wvb,
    bf16_t* __restrict__ Wob, float* __restrict__ ct, float* __restrict__ st)
{
    int b = blockIdx.x;
    if (b < 8192) {
        const float* src; bf16_t* dst; int off;
        if      (b < 2048) { src = q;  dst = Xq;  off = b; }
        else if (b < 4096) { src = k;  dst = Xk;  off = b - 2048; }
        else if (b < 6144) { src = v;  dst = Xv;  off = b - 4096; }
        else if (b < 6656) { src = wq; dst = Wqb; off = b - 6144; }
        else if (b < 7168) { src = wk; dst = Wkb; off = b - 6656; }
        else if (b < 7680) { src = wv; dst = Wvb; off = b - 7168; }
        else               { src = wo; dst = Wob; off = b - 7680; }
        int i = (off * 256 + threadIdx.x) * 8;
        float4 a = *(const float4*)(src + i);
        float4 c = *(const float4*)(src + i + 4);
        bf16x8 o;
        o[0]=(bf16_t)a.x; o[1]=(bf16_t)a.y; o[2]=(bf16_t)a.z; o[3]=(bf16_t)a.w;
        o[4]=(bf16_t)c.x; o[5]=(bf16_t)c.y; o[6]=(bf16_t)c.z; o[7]=(bf16_t)c.w;
        *(bf16x8*)(dst + i) = o;
    } else {
        int idx = (b - 8192) * 256 + threadIdx.x;   // 65536 = 2048*32
        int s = idx >> 5, i = idx & 31;
        float e = (float)(2 * i) / 64.0f;
        float invf = 1.0f / powf(10000.0f, e);
        float ang = (float)s * invf;
        ct[idx] = cosf(ang);
        st[idx] = sinf(ang);
    }
}

// stage one 256x64 bf16 tile (32 KB) into LDS, linear dest, source pre-swizzled
// (rule #21: LDS[row][oz] = G[row][oz ^ ((row&7)<<4)], read side applies same XOR)
#define STAGE_TILE(Gbase, rowoff, tt, Ldst) do {                                   \
    _Pragma("unroll")                                                              \
    for (int it_ = 0; it_ < 4; ++it_) {                                            \
        int row_ = (it_ << 6) + srow;                                              \
        const char* s_ = (const char*)(Gbase) + (((size_t)((rowoff) + row_)) << 11)\
                         + ((tt) << 7) + scol;                                     \
        gload_lds16(s_, (Ldst) + (it_ << 13) + (tid << 4));                        \
    }                                                                              \
} while (0)

// ---------------- QKV GEMM: 256x256 tile, BK=64, 8 waves, phase-interleaved ----------------
// out[m,n] = sum_k A[m,k]*W[n,k] + b[n]; epilogue -> [B,H,S,64] bf16 with RoPE for Q,K.
__global__ __launch_bounds__(512, 2) void k_gemm_qkv(
    const bf16_t* __restrict__ Xq, const bf16_t* __restrict__ Xk, const bf16_t* __restrict__ Xv,
    const bf16_t* __restrict__ Wqb, const bf16_t* __restrict__ Wkb, const bf16_t* __restrict__ Wvb,
    const float* __restrict__ bq, const float* __restrict__ bk, const float* __restrict__ bv,
    bf16_t* __restrict__ Qr, bf16_t* __restrict__ Kr, bf16_t* __restrict__ Vh,
    const float* __restrict__ ct, const float* __restrict__ st)
{
    __shared__ __align__(16) char smem[131072];   // [2 bufs][A 32K | B 32K]

    // XCD swizzle: 192 logical wgs, 24-chunk per XCD (192%8==0)
    int b0 = blockIdx.x;
    int wg = (b0 & 7) * 24 + (b0 >> 3);
    int id  = wg >> 6;                  // 0=Q 1=K 2=V
    int bid = wg & 63;

    const bf16_t* A   = (id==0) ? Xq  : (id==1) ? Xk  : Xv;
    const bf16_t* Wt  = (id==0) ? Wqb : (id==1) ? Wkb : Wvb;
    const float*  bias= (id==0) ? bq  : (id==1) ? bk  : bv;
    bf16_t* out = (id==0) ? Qr : (id==1) ? Kr : Vh;
    bool do_rope = (id < 2);

    int bm = (bid >> 2) << 8;           // M=4096 -> 16 row tiles
    int bn = (bid & 3) << 8;            // N=1024 -> 4 col tiles
    int tid = threadIdx.x;
    int l = tid & 63, wid = tid >> 6;   // 8 waves: 2M x 4N
    int wr = wid >> 2, wc = wid & 3;
    int lane16 = l & 15;
    int hi16 = (l >> 4) << 4;           // byte offset of lane's k-subgroup within 32-elem half
    int swz = (lane16 & 7) << 4;        // read-side XOR (row&7 == lane16&7 for all frags)
    int arow_base = ((wr << 7) + lane16) << 7;   // byte base of A frag row
    int brow_base = ((wc << 6) + lane16) << 7;   // byte base of B frag row

    int srow = tid >> 3;                // staging: row within 64-row chunk
    int scol = ((tid & 7) << 4) ^ ((srow & 7) << 4);   // pre-swizzled source col byte

    floatx4 acc[8][4];
    #pragma unroll
    for (int i = 0; i < 8; ++i)
        #pragma unroll
        for (int j = 0; j < 4; ++j) acc[i][j] = (floatx4){0.f,0.f,0.f,0.f};

    // prologue: stage tile0 -> buf0, tile1 -> buf1; wait tile0 (8 newest may fly)
    STAGE_TILE(A,  bm, 0, smem);
    STAGE_TILE(Wt, bn, 0, smem + 32768);
    STAGE_TILE(A,  bm, 1, smem + 65536);
    STAGE_TILE(Wt, bn, 1, smem + 65536 + 32768);
    asm volatile("s_waitcnt vmcnt(8)" ::: "memory");
    bar();

    bf16x8 bfrag[4][2];
    for (int t = 0; t < 16; ++t) {
        int c = t & 1;
        char* Ac = smem + (c << 16);
        char* Bc = Ac + 32768;
        char* An = smem + ((c ^ 1) << 16);
        char* Bn = An + 32768;
        bool do_stage = (t >= 1) && (t < 15);   // stage tile t+1 (tiles 2..15)

        #pragma unroll
        for (int p = 0; p < 4; ++p) {
            bf16x8 af[2][2];
            #pragma unroll
            for (int ip = 0; ip < 2; ++ip)
                #pragma unroll
                for (int s = 0; s < 2; ++s)
                    af[ip][s] = *(const bf16x8*)(Ac + arow_base + (((p<<1)+ip) << 11)
                                                 + (((s<<6) + hi16) ^ swz));
            if (p == 0) {
                #pragma unroll
                for (int j = 0; j < 4; ++j)
                    #pragma unroll
                    for (int s = 0; s < 2; ++s)
                        bfrag[j][s] = *(const bf16x8*)(Bc + brow_base + (j << 11)
                                                       + (((s<<6) + hi16) ^ swz));
                if (do_stage) STAGE_TILE(A, bm, t + 1, An);
            } else if (p == 1) {
                if (do_stage) STAGE_TILE(Wt, bn, t + 1, Bn);
            }
            bar();                       // enter MFMA cluster in lockstep (loads in flight)
            __builtin_amdgcn_s_setprio(1);
            #pragma unroll
            for (int ip = 0; ip < 2; ++ip)
                #pragma unroll
                for (int j = 0; j < 4; ++j) {
                    floatx4 tmp = __builtin_amdgcn_mfma_f32_16x16x32_bf16(
                                      af[ip][0], bfrag[j][0], acc[(p<<1)+ip][j], 0, 0, 0);
                    acc[(p<<1)+ip][j] = __builtin_amdgcn_mfma_f32_16x16x32_bf16(
                                      af[ip][1], bfrag[j][1], tmp, 0, 0, 0);
                }
            __builtin_amdgcn_s_setprio(0);
            if (p == 3) asm volatile("s_waitcnt vmcnt(0)" ::: "memory");  // tile t+1 landed
            bar();
        }
    }

    int h = (bn >> 6) + wc;             // 64-wide wave tile == one head
    int nb = bn + (wc << 6);
    #pragma unroll
    for (int i = 0; i < 8; ++i) {
        #pragma unroll
        for (int r = 0; r < 4; ++r) {
            int m  = bm + (wr << 7) + (i << 4) + ((l >> 4) << 2) + r;
            int b_ = m >> 11, s_ = m & 2047;
            size_t ob = ((((size_t)(b_ * NHEAD + h)) << 11) + s_) << 6;
            if (do_rope) {
                #pragma unroll
                for (int j = 0; j < 2; ++j) {
                    int d = (j << 4) + lane16;               // 0..31
                    float lo = acc[i][j][r]     + bias[nb + d];
                    float hv = acc[i][j + 2][r] + bias[nb + d + 32];
                    float cc = ct[(s_ << 5) + d], sn = st[(s_ << 5) + d];
                    out[ob + d]      = (bf16_t)(lo * cc - hv * sn);
                    out[ob + d + 32] = (bf16_t)(hv * cc + lo * sn);
                }
            } else {
                #pragma unroll
                for (int j = 0; j < 4; ++j) {
                    int d = (j << 4) + lane16;
                    out[ob + d] = (bf16_t)(acc[i][j][r] + bias[nb + d]);
                }
            }
        }
    }
}

// ---------------- O GEMM: 128x128 2-phase (unchanged from R2) ----------------
__global__ __launch_bounds__(256,2) void k_gemm_o(
    const bf16_t* __restrict__ A, const bf16_t* __restrict__ Wt,
    const float* __restrict__ bias, float* __restrict__ out)
{
    __shared__ bf16_t As[2][128*32];
    __shared__ bf16_t Bs[2][128*32];

    int b0 = blockIdx.x;
    int bid = (b0 & 7) * 32 + (b0 >> 3);
    int bm = (bid >> 3) << 7;
    int bn = (bid & 7) << 7;
    int tid = threadIdx.x;
    int l = tid & 63, wid = tid >> 6;
    int wr = wid >> 1, wc = wid & 1;
    int lane16 = l & 15, hi8 = (l >> 4) << 3;

    floatx4 acc[4][4];
    #pragma unroll
    for (int i = 0; i < 4; ++i)
        #pragma unroll
        for (int j = 0; j < 4; ++j) acc[i][j] = (floatx4){0.f,0.f,0.f,0.f};

    int srow = tid >> 2, scol = (tid & 3) << 3;
    const bf16_t* Ab = A  + ((size_t)(bm + srow) << 10) + scol;
    const bf16_t* Bb = Wt + ((size_t)(bn + srow) << 10) + scol;

    #pragma unroll
    for (int i2 = 0; i2 < 2; ++i2) {
        gload_lds16(Ab + (i2 << 16), &As[0][(tid + (i2<<8)) << 3]);
        gload_lds16(Bb + (i2 << 16), &Bs[0][(tid + (i2<<8)) << 3]);
    }
    __syncthreads();

    int cur = 0;
    for (int t = 0; t < 32; ++t) {
        if (t < 31) {
            int k0 = (t + 1) << 5;
            #pragma unroll
            for (int i2 = 0; i2 < 2; ++i2) {
                gload_lds16(Ab + k0 + (i2 << 16), &As[cur^1][(tid + (i2<<8)) << 3]);
                gload_lds16(Bb + k0 + (i2 << 16), &Bs[cur^1][(tid + (i2<<8)) << 3]);
            }
        }
        bf16x8 af[4], bfr[4];
        #pragma unroll
        for (int i = 0; i < 4; ++i)
            af[i]  = *(const bf16x8*)&As[cur][((wr<<6) + (i<<4) + lane16)*32 + hi8];
        #pragma unroll
        for (int j = 0; j < 4; ++j)
            bfr[j] = *(const bf16x8*)&Bs[cur][((wc<<6) + (j<<4) + lane16)*32 + hi8];
        #pragma unroll
        for (int i = 0; i < 4; ++i)
            #pragma unroll
            for (int j = 0; j < 4; ++j)
                acc[i][j] = __builtin_amdgcn_mfma_f32_16x16x32_bf16(af[i], bfr[j], acc[i][j], 0, 0, 0);
        __syncthreads();
        cur ^= 1;
    }

    #pragma unroll
    for (int i = 0; i < 4; ++i)
        #pragma unroll
        for (int r = 0; r < 4; ++r) {
            int m = bm + (wr<<6) + (i<<4) + ((l>>4)<<2) + r;
            #pragma unroll
            for (int j = 0; j < 4; ++j) {
                int n = bn + (wc<<6) + (j<<4) + lane16;
                out[((size_t)m << 10) + n] = acc[i][j][r] + bias[n];
            }
        }
}

// ---------------- sliding-window attention (unchanged) ----------------
__global__ __launch_bounds__(256,2) void k_attn(
    const bf16_t* __restrict__ Qr, const bf16_t* __restrict__ Kr,
    const bf16_t* __restrict__ Vh, bf16_t* __restrict__ AO)
{
    __shared__ char smem[51200];
    bf16_t* KsPs = (bf16_t*)smem;             // K window (swizzled), later aliased by P
    bf16_t* Vt   = (bf16_t*)(smem + 25600);   // V^T [64][200]

    int q0 = blockIdx.x << 6;
    int h = blockIdx.y, b_ = blockIdx.z;
    int kstart = q0 - 64; if (kstart < 0) kstart = 0;
    int kend   = q0 + 128; if (kend > 2048) kend = 2048;
    int NR = kend - kstart;                   // 128 or 192

    int tid = threadIdx.x, l = tid & 63, w = tid >> 6;
    int lane16 = l & 15, hi8 = (l >> 4) << 3;

    const bf16_t* Kbase = Kr + (((((size_t)(b_*NHEAD + h)) << 11) + kstart) << 6);
    const bf16_t* Vbase = Vh + (((((size_t)(b_*NHEAD + h)) << 11) + kstart) << 6);

    #pragma unroll
    for (int it = 0; it < 6; ++it) {
        int c = tid + (it << 8);
        int y = c << 4;                       // dest byte, 192 rows * 128B
        int row = y >> 7, oz = y & 127;
        int srw = row < NR ? row : NR - 1;
        int src = (srw << 7) + (oz ^ ((row & 7) << 4));
        gload_lds16((const char*)Kbase + src, (char*)KsPs + y);
    }
    #pragma unroll
    for (int it = 0; it < 6; ++it) {
        int c = tid + (it << 8);
        int jd = c >> 3, d0 = (c & 7) << 3;
        int js = jd < NR ? jd : NR - 1;
        bf16x8 v8 = *(const bf16x8*)(Vbase + (js << 6) + d0);
        #pragma unroll
        for (int t = 0; t < 8; ++t) Vt[(d0 + t) * 200 + jd] = v8[t];
    }
    int qs = q0 + (w << 4) + lane16;
    const bf16_t* Qbase = Qr + (((((size_t)(b_*NHEAD + h)) << 11) + qs) << 6);
    bf16x8 qf0 = *(const bf16x8*)(Qbase + hi8);
    bf16x8 qf1 = *(const bf16x8*)(Qbase + 32 + hi8);

    __syncthreads();

    floatx4 sc[12];
    #pragma unroll
    for (int kt = 0; kt < 12; ++kt) {
        int row = (kt << 4) + lane16;
        int base = (row << 7) + (hi8 << 1);
        int swz = (row & 7) << 4;
        bf16x8 kf0 = *(const bf16x8*)((const char*)KsPs + (base ^ swz));
        bf16x8 kf1 = *(const bf16x8*)((const char*)KsPs + ((base + 64) ^ swz));
        floatx4 a = (floatx4){0.f,0.f,0.f,0.f};
        a = __builtin_amdgcn_mfma_f32_16x16x32_bf16(qf0, kf0, a, 0, 0, 0);
        a = __builtin_amdgcn_mfma_f32_16x16x32_bf16(qf1, kf1, a, 0, 0, 0);
        sc[kt] = a;
    }

    float inv_[4];
    #pragma unroll
    for (int r = 0; r < 4; ++r) {
        int qrow = q0 + (w << 4) + ((l >> 4) << 2) + r;
        float mx = -1e30f;
        #pragma unroll
        for (int kt = 0; kt < 12; ++kt) {
            int ks = kstart + (kt << 4) + lane16;
            int dd = qrow - ks; dd = dd < 0 ? -dd : dd;
            float sv = sc[kt][r] * 0.125f;
            sv = (dd <= 50 && ks < kend) ? sv : -1e30f;
            sc[kt][r] = sv;
            mx = fmaxf(mx, sv);
        }
        #pragma unroll
        for (int off = 1; off < 16; off <<= 1) mx = fmaxf(mx, __shfl_xor(mx, off));
        float sum = 0.f;
        #pragma unroll
        for (int kt = 0; kt < 12; ++kt) {
            float p = __expf(sc[kt][r] - mx);
            sc[kt][r] = p;
            sum += p;
        }
        #pragma unroll
        for (int off = 1; off < 16; off <<= 1) sum += __shfl_xor(sum, off);
        inv_[r] = 1.0f / sum;
    }

    __syncthreads();   // all waves done reading K window -> P may overwrite it

    bf16_t* Pw = KsPs + w * 16 * 200;
    #pragma unroll
    for (int r = 0; r < 4; ++r) {
        int prow = ((l >> 4) << 2) + r;
        #pragma unroll
        for (int kt = 0; kt < 12; ++kt)
            Pw[prow * 200 + (kt << 4) + lane16] = (bf16_t)(sc[kt][r] * inv_[r]);
    }

    floatx4 oc[4];
    #pragma unroll
    for (int dt = 0; dt < 4; ++dt) oc[dt] = (floatx4){0.f,0.f,0.f,0.f};
    #pragma unroll
    for (int ks = 0; ks < 6; ++ks) {
        bf16x8 pf = *(const bf16x8*)&Pw[lane16 * 200 + (ks << 5) + hi8];
        #pragma unroll
        for (int dt = 0; dt < 4; ++dt) {
            bf16x8 vf = *(const bf16x8*)&Vt[((dt << 4) + lane16) * 200 + (ks << 5) + hi8];
            oc[dt] = __builtin_amdgcn_mfma_f32_16x16x32_bf16(pf, vf, oc[dt], 0, 0, 0);
        }
    }
    #pragma unroll
    for (int dt = 0; dt < 4; ++dt)
        #pragma unroll
        for (int r = 0; r < 4; ++r) {
            int qq = q0 + (w << 4) + ((l >> 4) << 2) + r;
            AO[(((size_t)(b_ * 2048 + qq)) << 10) + (h << 6) + (dt << 4) + lane16] = (bf16_t)oc[dt][r];
        }
}

extern "C" void kernel_launch(void* const* d_in, const int* in_sizes, int n_in,
                              void* d_out, int out_size, void* d_ws, size_t ws_size,
                              hipStream_t stream)
{
    const float* query = (const float*)d_in[0];
    const float* key_  = (const float*)d_in[1];
    const float* value = (const float*)d_in[2];
    const float* Wq = (const float*)d_in[3];
    const float* bq = (const float*)d_in[4];
    const float* Wk = (const float*)d_in[5];
    const float* bk = (const float*)d_in[6];
    const float* Wv = (const float*)d_in[7];
    const float* bv = (const float*)d_in[8];
    const float* Wo = (const float*)d_in[9];
    const float* bo = (const float*)d_in[10];

    char* ws = (char*)d_ws;
    bf16_t* Xq  = (bf16_t*)(ws);
    bf16_t* Xk  = (bf16_t*)(ws + 8388608);
    bf16_t* Xv  = (bf16_t*)(ws + 16777216);
    bf16_t* Wqb = (bf16_t*)(ws + 25165824);
    bf16_t* Wkb = (bf16_t*)(ws + 27262976);
    bf16_t* Wvb = (bf16_t*)(ws + 29360128);
    bf16_t* Wob = (bf16_t*)(ws + 31457280);
    bf16_t* Qr  = (bf16_t*)(ws + 33554432);
    bf16_t* Kr  = (bf16_t*)(ws + 41943040);
    bf16_t* Vh  = (bf16_t*)(ws + 50331648);
    bf16_t* AO  = (bf16_t*)(ws + 58720256);
    float*  ct  = (float*)(ws + 67108864);
    float*  st  = (float*)(ws + 67371008);

    k_prep<<<8448, 256, 0, stream>>>(query, key_, value, Wq, Wk, Wv, Wo,
                                     Xq, Xk, Xv, Wqb, Wkb, Wvb, Wob, ct, st);
    k_gemm_qkv<<<192, 512, 0, stream>>>(Xq, Xk, Xv, Wqb, Wkb, Wvb,
                                        bq, bk, bv, Qr, Kr, Vh, ct, st);
    k_attn<<<dim3(32, 16, 2), 256, 0, stream>>>(Qr, Kr, Vh, AO);
    k_gemm_o<<<256, 256, 0, stream>>>(AO, Wob, bo, (float*)d_out);
}

// Round 4
// 100.822 us; speedup vs baseline: 1.0101x; 1.0101x over previous
//
#include <hip/hip_runtime.h>
#include <hip/hip_bf16.h>
#include <math.h>

typedef __bf16 bf16_t;
typedef __bf16 bf16x8 __attribute__((ext_vector_type(8)));
typedef float floatx4 __attribute__((ext_vector_type(4)));
typedef unsigned int u32;

#define NHEAD 16

// async global->LDS, 16B per lane. Dest must be wave-uniform base + lane*16.
__device__ __forceinline__ void gload_lds16(const void* g, void* l) {
    __builtin_amdgcn_global_load_lds((const __attribute__((address_space(1))) u32*)g,
                                     (__attribute__((address_space(3))) u32*)l, 16, 0, 0);
}

// cvt 8 fp32 -> bf16x8 and ds_write_b128
__device__ __forceinline__ void write8(bf16_t* p, float4 a, float4 b) {
    bf16x8 o;
    o[0]=(bf16_t)a.x; o[1]=(bf16_t)a.y; o[2]=(bf16_t)a.z; o[3]=(bf16_t)a.w;
    o[4]=(bf16_t)b.x; o[5]=(bf16_t)b.y; o[6]=(bf16_t)b.z; o[7]=(bf16_t)b.w;
    *(bf16x8*)p = o;
}

// barrier with scheduler fences; caller supplies the waitcnt policy (counted, not drain)
__device__ __forceinline__ void bar_fenced() {
    __builtin_amdgcn_sched_barrier(0);
    __builtin_amdgcn_s_barrier();
    __builtin_amdgcn_sched_barrier(0);
}

// ---------------- prep: W fp32->bf16 (4 matrices) + RoPE table ----------------
// blocks [0,2048): W converts; [2048,2304): rope table.
__global__ __launch_bounds__(256) void k_prep(
    const float* __restrict__ wq, const float* __restrict__ wk,
    const float* __restrict__ wv, const float* __restrict__ wo,
    bf16_t* __restrict__ Wqb, bf16_t* __restrict__ Wkb, bf16_t* __restrict__ Wvb,
    bf16_t* __restrict__ Wob, float* __restrict__ ct, float* __restrict__ st)
{
    int b = blockIdx.x;
    if (b < 2048) {
        const float* src; bf16_t* dst; int off;
        if      (b < 512)  { src = wq; dst = Wqb; off = b; }
        else if (b < 1024) { src = wk; dst = Wkb; off = b - 512; }
        else if (b < 1536) { src = wv; dst = Wvb; off = b - 1024; }
        else               { src = wo; dst = Wob; off = b - 1536; }
        int i = (off * 256 + threadIdx.x) * 8;
        float4 a = *(const float4*)(src + i);
        float4 c = *(const float4*)(src + i + 4);
        write8(dst + i, a, c);
    } else {
        int idx = (b - 2048) * 256 + threadIdx.x;   // 65536 = 2048*32
        int s = idx >> 5, i = idx & 31;
        float e = (float)(2 * i) / 64.0f;
        float invf = 1.0f / powf(10000.0f, e);
        float ang = (float)s * invf;
        ct[idx] = cosf(ang);
        st[idx] = sinf(ang);
    }
}

// ---------------- QKV GEMM: 128x128 tile, BK=32, 3-slot LDS rotation, ----------------
// counted-vmcnt publish, A staged fp32->bf16 in-kernel (fuses the X convert).
// out[m,n] = sum_k A[m,k]*W[n,k] + b[n]; epilogue -> [B,H,S,64] bf16 with RoPE for Q,K.
__global__ __launch_bounds__(256,3) void k_gemm_qkv(
    const float* __restrict__ Xq, const float* __restrict__ Xk, const float* __restrict__ Xv,
    const bf16_t* __restrict__ Wqb, const bf16_t* __restrict__ Wkb, const bf16_t* __restrict__ Wvb,
    const float* __restrict__ bq, const float* __restrict__ bk, const float* __restrict__ bv,
    bf16_t* __restrict__ Qr, bf16_t* __restrict__ Kr, bf16_t* __restrict__ Vh,
    const float* __restrict__ ct, const float* __restrict__ st)
{
    __shared__ __align__(16) bf16_t As[3][4096];   // 3 x 8KB
    __shared__ __align__(16) bf16_t Bs[3][4096];

    // XCD swizzle: 768 logical wgs, 96-chunk per XCD
    int b0 = blockIdx.x;
    int wg = (b0 & 7) * 96 + (b0 >> 3);
    int id  = wg >> 8;                  // 0=Q 1=K 2=V
    int bid = wg & 255;

    const float*  A   = (id==0) ? Xq  : (id==1) ? Xk  : Xv;
    const bf16_t* Wt  = (id==0) ? Wqb : (id==1) ? Wkb : Wvb;
    const float*  bias= (id==0) ? bq  : (id==1) ? bk  : bv;
    bf16_t* out = (id==0) ? Qr : (id==1) ? Kr : Vh;
    bool do_rope = (id < 2);

    int bm = (bid >> 3) << 7;           // M=4096 -> 32 row tiles
    int bn = (bid & 7) << 7;            // N=1024 -> 8 col tiles
    int tid = threadIdx.x;
    int l = tid & 63, wid = tid >> 6;
    int wr = wid >> 1, wc = wid & 1;
    int lane16 = l & 15, hi8 = (l >> 4) << 3;

    floatx4 acc[4][4];
    #pragma unroll
    for (int i = 0; i < 4; ++i)
        #pragma unroll
        for (int j = 0; j < 4; ++j) acc[i][j] = (floatx4){0.f,0.f,0.f,0.f};

    // staging coords: thread covers dest chunks c0,c1 (16B each); row=c>>2, col=(c&3)*8
    int c0 = tid, c1 = tid + 256;
    int row0 = c0 >> 2, col0 = (c0 & 3) << 3;
    int row1 = c1 >> 2, col1 = (c1 & 3) << 3;
    const float*  Ap0 = A  + ((size_t)(bm + row0) << 10) + col0;
    const float*  Ap1 = A  + ((size_t)(bm + row1) << 10) + col1;
    const bf16_t* Bp0 = Wt + ((size_t)(bn + row0) << 10) + col0;
    const bf16_t* Bp1 = Wt + ((size_t)(bn + row1) << 10) + col1;

    // prologue: tiles 0,1 into slots 0,1 (full drain once)
    {
        float4 p0 = *(const float4*)(Ap0);      float4 p1 = *(const float4*)(Ap0 + 4);
        float4 p2 = *(const float4*)(Ap1);      float4 p3 = *(const float4*)(Ap1 + 4);
        gload_lds16(Bp0, &Bs[0][c0 << 3]);
        gload_lds16(Bp1, &Bs[0][c1 << 3]);
        float4 q0 = *(const float4*)(Ap0 + 32); float4 q1 = *(const float4*)(Ap0 + 36);
        float4 q2 = *(const float4*)(Ap1 + 32); float4 q3 = *(const float4*)(Ap1 + 36);
        gload_lds16(Bp0 + 32, &Bs[1][c0 << 3]);
        gload_lds16(Bp1 + 32, &Bs[1][c1 << 3]);
        write8(&As[0][c0 << 3], p0, p1);  write8(&As[0][c1 << 3], p2, p3);
        write8(&As[1][c0 << 3], q0, q1);  write8(&As[1][c1 << 3], q2, q3);
        asm volatile("s_waitcnt vmcnt(0) lgkmcnt(0)" ::: "memory");
        bar_fenced();
    }

    int cur = 0, nxt2 = 2;
    for (int t = 0; t < 32; ++t) {
        const bf16_t* Ac = As[cur];
        const bf16_t* Bc = Bs[cur];
        bf16_t* Ast = As[nxt2];
        bf16_t* Bst = Bs[nxt2];
        bool stg = (t < 30);

        float4 p0, p1, p2, p3;
        if (stg) {                       // issue-early: loads for tile t+2
            int k0 = (t + 2) << 5;
            p0 = *(const float4*)(Ap0 + k0);      p1 = *(const float4*)(Ap0 + k0 + 4);
            p2 = *(const float4*)(Ap1 + k0);      p3 = *(const float4*)(Ap1 + k0 + 4);
            gload_lds16(Bp0 + k0, &Bst[c0 << 3]);
            gload_lds16(Bp1 + k0, &Bst[c1 << 3]);
        }

        bf16x8 af[4], bfr[4];
        #pragma unroll
        for (int i = 0; i < 4; ++i)
            af[i]  = *(const bf16x8*)&Ac[((wr<<6) + (i<<4) + lane16)*32 + hi8];
        #pragma unroll
        for (int j = 0; j < 4; ++j)
            bfr[j] = *(const bf16x8*)&Bc[((wc<<6) + (j<<4) + lane16)*32 + hi8];
        #pragma unroll
        for (int i = 0; i < 4; ++i)
            #pragma unroll
            for (int j = 0; j < 4; ++j)
                acc[i][j] = __builtin_amdgcn_mfma_f32_16x16x32_bf16(af[i], bfr[j], acc[i][j], 0, 0, 0);

        if (stg) {                       // write-late: cvt waits only the 4 A-loads
            write8(&Ast[c0 << 3], p0, p1);
            write8(&Ast[c1 << 3], p2, p3);
        }
        if (t < 31) {
            // publish tile t+1: its loads are older than everything issued this step;
            // the cvt's implicit vmcnt already covered them. Only drain at the tail.
            if (!stg) asm volatile("s_waitcnt vmcnt(0)" ::: "memory");
            asm volatile("s_waitcnt lgkmcnt(0)" ::: "memory");
            bar_fenced();
        }
        cur  = (cur  == 2) ? 0 : cur + 1;
        nxt2 = (nxt2 == 2) ? 0 : nxt2 + 1;
    }

    int h = (bn + (wc<<6)) >> 6;        // head index (64-wide wave tile == one head)
    #pragma unroll
    for (int i = 0; i < 4; ++i) {
        #pragma unroll
        for (int r = 0; r < 4; ++r) {
            int m  = bm + (wr<<6) + (i<<4) + ((l>>4)<<2) + r;
            int b_ = m >> 11, s_ = m & 2047;
            size_t ob = ((((size_t)(b_*NHEAD + h)) << 11) + s_) << 6;
            if (do_rope) {
                #pragma unroll
                for (int j = 0; j < 2; ++j) {
                    int d = (j<<4) + lane16;                 // 0..31
                    float lo = acc[i][j][r]   + bias[bn + (wc<<6) + d];
                    float hv = acc[i][j+2][r] + bias[bn + (wc<<6) + d + 32];
                    float c = ct[(s_<<5) + d], sn = st[(s_<<5) + d];
                    out[ob + d]      = (bf16_t)(lo*c - hv*sn);
                    out[ob + d + 32] = (bf16_t)(hv*c + lo*sn);
                }
            } else {
                #pragma unroll
                for (int j = 0; j < 4; ++j) {
                    int d = (j<<4) + lane16;
                    out[ob + d] = (bf16_t)(acc[i][j][r] + bias[bn + (wc<<6) + d]);
                }
            }
        }
    }
}

// ---------------- O GEMM: 128x128, BK=32, 3-slot rotation, counted vmcnt(4) ----------------
__global__ __launch_bounds__(256,3) void k_gemm_o(
    const bf16_t* __restrict__ A, const bf16_t* __restrict__ Wt,
    const float* __restrict__ bias, float* __restrict__ out)
{
    __shared__ __align__(16) bf16_t As[3][4096];
    __shared__ __align__(16) bf16_t Bs[3][4096];

    int b0 = blockIdx.x;
    int bid = (b0 & 7) * 32 + (b0 >> 3);   // 256 wgs, 32-chunk per XCD
    int bm = (bid >> 3) << 7;
    int bn = (bid & 7) << 7;
    int tid = threadIdx.x;
    int l = tid & 63, wid = tid >> 6;
    int wr = wid >> 1, wc = wid & 1;
    int lane16 = l & 15, hi8 = (l >> 4) << 3;

    floatx4 acc[4][4];
    #pragma unroll
    for (int i = 0; i < 4; ++i)
        #pragma unroll
        for (int j = 0; j < 4; ++j) acc[i][j] = (floatx4){0.f,0.f,0.f,0.f};

    int c0 = tid, c1 = tid + 256;
    int row0 = c0 >> 2, col0 = (c0 & 3) << 3;
    int row1 = c1 >> 2, col1 = (c1 & 3) << 3;
    const bf16_t* Ap0 = A  + ((size_t)(bm + row0) << 10) + col0;
    const bf16_t* Ap1 = A  + ((size_t)(bm + row1) << 10) + col1;
    const bf16_t* Bp0 = Wt + ((size_t)(bn + row0) << 10) + col0;
    const bf16_t* Bp1 = Wt + ((size_t)(bn + row1) << 10) + col1;

    // prologue: tile0 -> slot0, tile1 -> slot1; counted wait (tile1 stays in flight)
    gload_lds16(Ap0, &As[0][c0 << 3]);  gload_lds16(Ap1, &As[0][c1 << 3]);
    gload_lds16(Bp0, &Bs[0][c0 << 3]);  gload_lds16(Bp1, &Bs[0][c1 << 3]);
    gload_lds16(Ap0 + 32, &As[1][c0 << 3]);  gload_lds16(Ap1 + 32, &As[1][c1 << 3]);
    gload_lds16(Bp0 + 32, &Bs[1][c0 << 3]);  gload_lds16(Bp1 + 32, &Bs[1][c1 << 3]);
    asm volatile("s_waitcnt vmcnt(4)" ::: "memory");
    bar_fenced();

    int cur = 0, nxt2 = 2;
    for (int t = 0; t < 32; ++t) {
        const bf16_t* Ac = As[cur];
        const bf16_t* Bc = Bs[cur];
        bf16_t* Ast = As[nxt2];
        bf16_t* Bst = Bs[nxt2];
        bool stg = (t < 30);

        if (stg) {
            int k0 = (t + 2) << 5;
            gload_lds16(Ap0 + k0, &Ast[c0 << 3]);  gload_lds16(Ap1 + k0, &Ast[c1 << 3]);
            gload_lds16(Bp0 + k0, &Bst[c0 << 3]);  gload_lds16(Bp1 + k0, &Bst[c1 << 3]);
        }

        bf16x8 af[4], bfr[4];
        #pragma unroll
        for (int i = 0; i < 4; ++i)
            af[i]  = *(const bf16x8*)&Ac[((wr<<6) + (i<<4) + lane16)*32 + hi8];
        #pragma unroll
        for (int j = 0; j < 4; ++j)
            bfr[j] = *(const bf16x8*)&Bc[((wc<<6) + (j<<4) + lane16)*32 + hi8];
        #pragma unroll
        for (int i = 0; i < 4; ++i)
            #pragma unroll
            for (int j = 0; j < 4; ++j)
                acc[i][j] = __builtin_amdgcn_mfma_f32_16x16x32_bf16(af[i], bfr[j], acc[i][j], 0, 0, 0);

        if (t < 31) {
            if (stg) asm volatile("s_waitcnt vmcnt(4)" ::: "memory");  // t+1 landed, t+2 flies
            else     asm volatile("s_waitcnt vmcnt(0)" ::: "memory");  // tail
            bar_fenced();
        }
        cur  = (cur  == 2) ? 0 : cur + 1;
        nxt2 = (nxt2 == 2) ? 0 : nxt2 + 1;
    }

    #pragma unroll
    for (int i = 0; i < 4; ++i)
        #pragma unroll
        for (int r = 0; r < 4; ++r) {
            int m = bm + (wr<<6) + (i<<4) + ((l>>4)<<2) + r;
            #pragma unroll
            for (int j = 0; j < 4; ++j) {
                int n = bn + (wc<<6) + (j<<4) + lane16;
                out[((size_t)m << 10) + n] = acc[i][j][r] + bias[n];
            }
        }
}

// ---------------- sliding-window attention (unchanged, proven) ----------------
__global__ __launch_bounds__(256,2) void k_attn(
    const bf16_t* __restrict__ Qr, const bf16_t* __restrict__ Kr,
    const bf16_t* __restrict__ Vh, bf16_t* __restrict__ AO)
{
    __shared__ char smem[51200];
    bf16_t* KsPs = (bf16_t*)smem;             // K window (swizzled), later aliased by P
    bf16_t* Vt   = (bf16_t*)(smem + 25600);   // V^T [64][200]

    int q0 = blockIdx.x << 6;
    int h = blockIdx.y, b_ = blockIdx.z;
    int kstart = q0 - 64; if (kstart < 0) kstart = 0;
    int kend   = q0 + 128; if (kend > 2048) kend = 2048;
    int NR = kend - kstart;                   // 128 or 192

    int tid = threadIdx.x, l = tid & 63, w = tid >> 6;
    int lane16 = l & 15, hi8 = (l >> 4) << 3;

    const bf16_t* Kbase = Kr + (((((size_t)(b_*NHEAD + h)) << 11) + kstart) << 6);
    const bf16_t* Vbase = Vh + (((((size_t)(b_*NHEAD + h)) << 11) + kstart) << 6);

    #pragma unroll
    for (int it = 0; it < 6; ++it) {
        int c = tid + (it << 8);
        int y = c << 4;                       // dest byte, 192 rows * 128B
        int row = y >> 7, oz = y & 127;
        int srw = row < NR ? row : NR - 1;
        int src = (srw << 7) + (oz ^ ((row & 7) << 4));
        gload_lds16((const char*)Kbase + src, (char*)KsPs + y);
    }
    #pragma unroll
    for (int it = 0; it < 6; ++it) {
        int c = tid + (it << 8);
        int jd = c >> 3, d0 = (c & 7) << 3;
        int js = jd < NR ? jd : NR - 1;
        bf16x8 v8 = *(const bf16x8*)(Vbase + (js << 6) + d0);
        #pragma unroll
        for (int t = 0; t < 8; ++t) Vt[(d0 + t) * 200 + jd] = v8[t];
    }
    int qs = q0 + (w << 4) + lane16;
    const bf16_t* Qbase = Qr + (((((size_t)(b_*NHEAD + h)) << 11) + qs) << 6);
    bf16x8 qf0 = *(const bf16x8*)(Qbase + hi8);
    bf16x8 qf1 = *(const bf16x8*)(Qbase + 32 + hi8);

    __syncthreads();

    floatx4 sc[12];
    #pragma unroll
    for (int kt = 0; kt < 12; ++kt) {
        int row = (kt << 4) + lane16;
        int base = (row << 7) + (hi8 << 1);
        int swz = (row & 7) << 4;
        bf16x8 kf0 = *(const bf16x8*)((const char*)KsPs + (base ^ swz));
        bf16x8 kf1 = *(const bf16x8*)((const char*)KsPs + ((base + 64) ^ swz));
        floatx4 a = (floatx4){0.f,0.f,0.f,0.f};
        a = __builtin_amdgcn_mfma_f32_16x16x32_bf16(qf0, kf0, a, 0, 0, 0);
        a = __builtin_amdgcn_mfma_f32_16x16x32_bf16(qf1, kf1, a, 0, 0, 0);
        sc[kt] = a;
    }

    float inv_[4];
    #pragma unroll
    for (int r = 0; r < 4; ++r) {
        int qrow = q0 + (w << 4) + ((l >> 4) << 2) + r;
        float mx = -1e30f;
        #pragma unroll
        for (int kt = 0; kt < 12; ++kt) {
            int ks = kstart + (kt << 4) + lane16;
            int dd = qrow - ks; dd = dd < 0 ? -dd : dd;
            float sv = sc[kt][r] * 0.125f;
            sv = (dd <= 50 && ks < kend) ? sv : -1e30f;
            sc[kt][r] = sv;
            mx = fmaxf(mx, sv);
        }
        #pragma unroll
        for (int off = 1; off < 16; off <<= 1) mx = fmaxf(mx, __shfl_xor(mx, off));
        float sum = 0.f;
        #pragma unroll
        for (int kt = 0; kt < 12; ++kt) {
            float p = __expf(sc[kt][r] - mx);
            sc[kt][r] = p;
            sum += p;
        }
        #pragma unroll
        for (int off = 1; off < 16; off <<= 1) sum += __shfl_xor(sum, off);
        inv_[r] = 1.0f / sum;
    }

    __syncthreads();   // all waves done reading K window -> P may overwrite it

    bf16_t* Pw = KsPs + w * 16 * 200;
    #pragma unroll
    for (int r = 0; r < 4; ++r) {
        int prow = ((l >> 4) << 2) + r;
        #pragma unroll
        for (int kt = 0; kt < 12; ++kt)
            Pw[prow * 200 + (kt << 4) + lane16] = (bf16_t)(sc[kt][r] * inv_[r]);
    }

    floatx4 oc[4];
    #pragma unroll
    for (int dt = 0; dt < 4; ++dt) oc[dt] = (floatx4){0.f,0.f,0.f,0.f};
    #pragma unroll
    for (int ks = 0; ks < 6; ++ks) {
        bf16x8 pf = *(const bf16x8*)&Pw[lane16 * 200 + (ks << 5) + hi8];
        #pragma unroll
        for (int dt = 0; dt < 4; ++dt) {
            bf16x8 vf = *(const bf16x8*)&Vt[((dt << 4) + lane16) * 200 + (ks << 5) + hi8];
            oc[dt] = __builtin_amdgcn_mfma_f32_16x16x32_bf16(pf, vf, oc[dt], 0, 0, 0);
        }
    }
    #pragma unroll
    for (int dt = 0; dt < 4; ++dt)
        #pragma unroll
        for (int r = 0; r < 4; ++r) {
            int qq = q0 + (w << 4) + ((l >> 4) << 2) + r;
            AO[(((size_t)(b_ * 2048 + qq)) << 10) + (h << 6) + (dt << 4) + lane16] = (bf16_t)oc[dt][r];
        }
}

extern "C" void kernel_launch(void* const* d_in, const int* in_sizes, int n_in,
                              void* d_out, int out_size, void* d_ws, size_t ws_size,
                              hipStream_t stream)
{
    const float* query = (const float*)d_in[0];
    const float* key_  = (const float*)d_in[1];
    const float* value = (const float*)d_in[2];
    const float* Wq = (const float*)d_in[3];
    const float* bq = (const float*)d_in[4];
    const float* Wk = (const float*)d_in[5];
    const float* bk = (const float*)d_in[6];
    const float* Wv = (const float*)d_in[7];
    const float* bv = (const float*)d_in[8];
    const float* Wo = (const float*)d_in[9];
    const float* bo = (const float*)d_in[10];

    char* ws = (char*)d_ws;
    bf16_t* Wqb = (bf16_t*)(ws);
    bf16_t* Wkb = (bf16_t*)(ws + 2097152);
    bf16_t* Wvb = (bf16_t*)(ws + 4194304);
    bf16_t* Wob = (bf16_t*)(ws + 6291456);
    bf16_t* Qr  = (bf16_t*)(ws + 8388608);
    bf16_t* Kr  = (bf16_t*)(ws + 16777216);
    bf16_t* Vh  = (bf16_t*)(ws + 25165824);
    bf16_t* AO  = (bf16_t*)(ws + 33554432);
    float*  ct  = (float*)(ws + 41943040);
    float*  st  = (float*)(ws + 42205184);

    k_prep<<<2304, 256, 0, stream>>>(Wq, Wk, Wv, Wo, Wqb, Wkb, Wvb, Wob, ct, st);
    k_gemm_qkv<<<768, 256, 0, stream>>>(query, key_, value, Wqb, Wkb, Wvb,
                                        bq, bk, bv, Qr, Kr, Vh, ct, st);
    k_attn<<<dim3(32, 16, 2), 256, 0, stream>>>(Qr, Kr, Vh, AO);
    k_gemm_o<<<256, 256, 0, stream>>>(AO, Wob, bo, (float*)d_out);
}